// Round 11
// baseline (225.513 us; speedup 1.0000x reference)
//
#include <hip/hip_runtime.h>
#include <hip/hip_fp16.h>

#define N_NODES 100000
#define F_IN 128
#define H 16
#define NBIN 391           // ceil(N_NODES/256); bin b owns nodes [b*256, b*256+256)
#define BINCAP 4608        // per-bin record capacity (mean 4096, +8 sigma)
#define ECHUNK 2048        // edges per binfill block (256 thr x 8)
#define LIN1B 782          // (N_NODES+127)/128 lin1 blocks in fused front
#define QSCALE 4096.0f     // int16 fixed-point scale (range ±8, err 1.2e-4)
#define QINV (1.0f / 4096.0f)

// Pack two floats to int16 fixed-point (round-nearest, clamped)
__device__ inline unsigned int packi16(float a, float b) {
  int ia = __float2int_rn(fminf(fmaxf(a * QSCALE, -32767.f), 32767.f));
  int ib = __float2int_rn(fminf(fmaxf(b * QSCALE, -32767.f), 32767.f));
  return (unsigned int)((ia & 0xffff) | (ib << 16));
}

// ---------------------------------------------------------------------------
// k_init: binCur[b] = b * BINCAP  (record-region cursors)
// ---------------------------------------------------------------------------
__global__ void __launch_bounds__(512) k_init(int* __restrict__ binCur) {
  int t = threadIdx.x;
  if (t < NBIN) binCur[t] = t * BINCAP;
}

// ---------------------------------------------------------------------------
// k_front: heterogeneous fusion of lin1 and binfill (independent stages).
// Blocks [0, LIN1B): lin1 — y1l = i16fx(x @ W1l), y1r = x @ W1r (fp32),
//   split-K 256 thr = 128 nodes x 2 K-halves, W scalar-loaded, LDS reduce.
// Blocks [LIN1B, ...): binfill — radix pass 1, records (src<<8|dstLow)
//   binned by dst>>8, per-block LDS hist + one global cursor atomicAdd per
//   (block,bin), ranged sequential writes.
// Overlap rationale: lin1 is VALU/L1-bound, binfill is LDS-atomic/write-
// bound; co-residency hides the shorter under the longer.
// ---------------------------------------------------------------------------
__global__ void __launch_bounds__(256) k_front(
    const float* __restrict__ x, const float* __restrict__ W1l,
    const float* __restrict__ W1r, unsigned short* __restrict__ y1l,
    float* __restrict__ y1r, const int* __restrict__ src,
    const int* __restrict__ dst, int* __restrict__ binCur,
    int* __restrict__ recs, int E) {
  __shared__ float smem[2 * H * 128];   // 16 KB, unioned across branches
  int t = threadIdx.x;
  if (blockIdx.x < LIN1B) {
    // ---------------- lin1 ----------------
    float* red = smem;
    int part = __builtin_amdgcn_readfirstlane(t >> 7);   // 0/1, wave-uniform
    int ln = t & 127;
    int n = blockIdx.x * 128 + ln;
    int nc = (n < N_NODES) ? n : (N_NODES - 1);
    const float4* xr = (const float4*)(x + (size_t)nc * F_IN + part * (F_IN / 2));
    float4 xv[16];
#pragma unroll
    for (int j = 0; j < 16; ++j) xv[j] = xr[j];
    const float* Wl = W1l + part * (F_IN / 2) * H;       // SGPR base
    const float* Wr = W1r + part * (F_IN / 2) * H;
    float al[H], ar[H];
#pragma unroll
    for (int c = 0; c < H; ++c) { al[c] = 0.f; ar[c] = 0.f; }
#pragma unroll
    for (int j = 0; j < 16; ++j) {
      float xs[4] = {xv[j].x, xv[j].y, xv[j].z, xv[j].w};
#pragma unroll
      for (int jj = 0; jj < 4; ++jj) {
        int k = j * 4 + jj;
#pragma unroll
        for (int c = 0; c < H; ++c) {
          al[c] = fmaf(xs[jj], Wl[k * H + c], al[c]);
          ar[c] = fmaf(xs[jj], Wr[k * H + c], ar[c]);
        }
      }
    }
    if (part == 1) {
#pragma unroll
      for (int c = 0; c < H; ++c) {
        red[c * 128 + ln] = al[c];
        red[(H + c) * 128 + ln] = ar[c];
      }
    }
    __syncthreads();
    if (part == 0 && n < N_NODES) {
#pragma unroll
      for (int c = 0; c < H; ++c) {
        al[c] += red[c * 128 + ln];
        ar[c] += red[(H + c) * 128 + ln];
      }
      uint4 w0, w1;
      w0.x = packi16(al[0], al[1]);  w0.y = packi16(al[2], al[3]);
      w0.z = packi16(al[4], al[5]);  w0.w = packi16(al[6], al[7]);
      w1.x = packi16(al[8], al[9]);  w1.y = packi16(al[10], al[11]);
      w1.z = packi16(al[12], al[13]); w1.w = packi16(al[14], al[15]);
      uint4* ol = (uint4*)(y1l + (size_t)n * H);   // 32 B row
      ol[0] = w0;
      ol[1] = w1;
      float4* orr = (float4*)(y1r + (size_t)n * H);
#pragma unroll
      for (int q = 0; q < 4; ++q)
        orr[q] = make_float4(ar[4 * q], ar[4 * q + 1], ar[4 * q + 2], ar[4 * q + 3]);
    }
  } else {
    // ---------------- binfill ----------------
    int* hist = (int*)smem;        // 512 ints
    int* gbase = hist + 512;       // 512 ints
    int* cnt2 = gbase + 512;       // 512 ints
    hist[t] = 0; hist[256 + t] = 0;
    cnt2[t] = 0; cnt2[256 + t] = 0;
    __syncthreads();
    int base = (blockIdx.x - LIN1B) * ECHUNK;
    int rec[8], bin[8];
#pragma unroll
    for (int j = 0; j < 8; ++j) {
      int e = base + j * 256 + t;
      if (e < E) {
        int s = src[e];
        int d = dst[e];
        rec[j] = (s << 8) | (d & 255);
        bin[j] = d >> 8;
        atomicAdd(&hist[bin[j]], 1);
      } else {
        bin[j] = -1;
      }
    }
    __syncthreads();
    for (int u = t; u < NBIN; u += 256) {
      int c = hist[u];
      gbase[u] = (c > 0) ? atomicAdd(&binCur[u], c) : 0;
    }
    __syncthreads();
#pragma unroll
    for (int j = 0; j < 8; ++j) {
      if (bin[j] >= 0) {
        int loc = atomicAdd(&cnt2[bin[j]], 1);
        int slot = gbase[bin[j]] + loc;
        if (slot < (bin[j] + 1) * BINCAP)  // safety clamp (never expected)
          recs[slot] = rec[j];
      }
    }
  }
}

// ---------------------------------------------------------------------------
// k_group: one block per bin. Load records to LDS, histogram dstLow,
// scan -> deg/rowBeg, scatter src ids directly to final global CSR slots.
// Row-internal order nondeterministic — fine: downstream accumulation is
// integer (order-invariant).
// ---------------------------------------------------------------------------
__global__ void __launch_bounds__(512) k_group(
    int* __restrict__ recs, const int* __restrict__ binCur,
    int* __restrict__ deg, int* __restrict__ rowBeg) {
  __shared__ int lrec[BINCAP];
  __shared__ int hist[256];
  __shared__ int off[256];       // inclusive scan; (off - hist) = exclusive
  __shared__ int cur[256];
  int t = threadIdx.x;
  int b = blockIdx.x;
  int rbase = b * BINCAP;
  int R = binCur[b] - rbase;
  if (R > BINCAP) R = BINCAP;
  if (t < 256) hist[t] = 0;
  __syncthreads();
#pragma unroll
  for (int j = 0; j < 9; ++j) {
    int idx = j * 512 + t;
    if (idx < R) {
      int r = recs[rbase + idx];
      lrec[idx] = r;
      atomicAdd(&hist[r & 255], 1);
    }
  }
  __syncthreads();
  if (t < 256) off[t] = hist[t];
  __syncthreads();
  for (int o = 1; o < 256; o <<= 1) {
    int u = 0;
    if (t < 256 && t >= o) u = off[t - o];
    __syncthreads();
    if (t < 256) off[t] += u;
    __syncthreads();
  }
  if (t < 256) {
    int ex = off[t] - hist[t];
    cur[t] = ex;
    int n = (b << 8) + t;
    if (n < N_NODES) {
      deg[n] = hist[t];
      rowBeg[n] = rbase + ex;
    }
  }
  __syncthreads();
#pragma unroll
  for (int j = 0; j < 9; ++j) {
    int idx = j * 512 + t;
    if (idx < R) {
      int r = lrec[idx];
      int slot = atomicAdd(&cur[r & 255], 1);
      recs[rbase + slot] = r >> 8;   // direct final write (L2-local region)
    }
  }
}

// ---------------------------------------------------------------------------
// gather1 (4 lanes/node): lane q owns channels 4q..4q+3. Per neighbor one
// uint2 (4 int16) load; int32 accumulation (exact, order-invariant).
// 8-deep neighbor unroll: two up-front index loads keep 8 data loads in
// flight. Epilogue: h1 = relu(mean + b1 + y1r); W2 matvec via width-4
// shuffle transpose; z2l = i16fx, z2r = fp32.
// ---------------------------------------------------------------------------
__global__ void __launch_bounds__(256) k_gather1(
    const int* __restrict__ srcSorted, const int* __restrict__ deg,
    const int* __restrict__ rowBeg, const unsigned short* __restrict__ y1l,
    const float* __restrict__ y1r, const float* __restrict__ b1,
    const float* __restrict__ W2l, const float* __restrict__ W2r,
    unsigned short* __restrict__ z2l, float* __restrict__ z2r) {
  int tid = blockIdx.x * 256 + threadIdx.x;
  int n = tid >> 2;
  int q = tid & 3;
  if (n >= N_NODES) return;
  int beg = rowBeg[n];
  int dg = deg[n];
  int end = beg + dg;
  int acc0 = 0, acc1 = 0, acc2 = 0, acc3 = 0;
  int i = beg;
  for (; i + 8 <= end; i += 8) {
    int sqa = srcSorted[i + q];
    int sqb = srcSorted[i + 4 + q];
#pragma unroll
    for (int j = 0; j < 4; ++j) {
      int sa = __shfl(sqa, j, 4);
      int sb = __shfl(sqb, j, 4);
      uint2 va = *(const uint2*)(y1l + (size_t)sa * H + q * 4);
      uint2 vb = *(const uint2*)(y1l + (size_t)sb * H + q * 4);
      acc0 += (((int)(va.x << 16)) >> 16) + (((int)(vb.x << 16)) >> 16);
      acc1 += (((int)va.x) >> 16) + (((int)vb.x) >> 16);
      acc2 += (((int)(va.y << 16)) >> 16) + (((int)(vb.y << 16)) >> 16);
      acc3 += (((int)va.y) >> 16) + (((int)vb.y) >> 16);
    }
  }
  for (; i + 4 <= end; i += 4) {
    int sq = srcSorted[i + q];
#pragma unroll
    for (int j = 0; j < 4; ++j) {
      int sj = __shfl(sq, j, 4);
      uint2 v = *(const uint2*)(y1l + (size_t)sj * H + q * 4);
      acc0 += ((int)(v.x << 16)) >> 16;
      acc1 += ((int)v.x) >> 16;
      acc2 += ((int)(v.y << 16)) >> 16;
      acc3 += ((int)v.y) >> 16;
    }
  }
  for (; i < end; ++i) {
    int sj = srcSorted[i];
    uint2 v = *(const uint2*)(y1l + (size_t)sj * H + q * 4);
    acc0 += ((int)(v.x << 16)) >> 16;
    acc1 += ((int)v.x) >> 16;
    acc2 += ((int)(v.y << 16)) >> 16;
    acc3 += ((int)v.y) >> 16;
  }
  float s = (1.f / fmaxf((float)dg, 1.f)) * QINV;
  float4 yr = *(const float4*)(y1r + (size_t)n * H + q * 4);
  float4 bb = *(const float4*)(b1 + q * 4);
  float h1x = fmaxf(fmaf((float)acc0, s, bb.x + yr.x), 0.f);
  float h1y = fmaxf(fmaf((float)acc1, s, bb.y + yr.y), 0.f);
  float h1z = fmaxf(fmaf((float)acc2, s, bb.z + yr.z), 0.f);
  float h1w = fmaxf(fmaf((float)acc3, s, bb.w + yr.w), 0.f);
  float zl0 = 0.f, zl1 = 0.f, zl2 = 0.f, zl3 = 0.f;
  float zr0 = 0.f, zr1 = 0.f, zr2 = 0.f, zr3 = 0.f;
#pragma unroll
  for (int sl = 0; sl < 4; ++sl) {
    float hx = __shfl(h1x, sl, 4);
    float hy = __shfl(h1y, sl, 4);
    float hz = __shfl(h1z, sl, 4);
    float hw = __shfl(h1w, sl, 4);
    float hk4[4] = {hx, hy, hz, hw};
#pragma unroll
    for (int j = 0; j < 4; ++j) {
      int k = sl * 4 + j;               // h1 channel index
      float4 wl = *(const float4*)(W2l + k * H + q * 4);
      float4 wr = *(const float4*)(W2r + k * H + q * 4);
      float hk = hk4[j];
      zl0 = fmaf(hk, wl.x, zl0); zl1 = fmaf(hk, wl.y, zl1);
      zl2 = fmaf(hk, wl.z, zl2); zl3 = fmaf(hk, wl.w, zl3);
      zr0 = fmaf(hk, wr.x, zr0); zr1 = fmaf(hk, wr.y, zr1);
      zr2 = fmaf(hk, wr.z, zr2); zr3 = fmaf(hk, wr.w, zr3);
    }
  }
  uint2 pk;
  pk.x = packi16(zl0, zl1);
  pk.y = packi16(zl2, zl3);
  *(uint2*)(z2l + (size_t)n * H + q * 4) = pk;
  *(float4*)(z2r + (size_t)n * H + q * 4) = make_float4(zr0, zr1, zr2, zr3);
}

// ---------------------------------------------------------------------------
// gather2 (4 lanes/node): h2 = fp16(mean(z2l_nbrs) + b2 + z2r)
// ---------------------------------------------------------------------------
__global__ void __launch_bounds__(256) k_gather2(
    const int* __restrict__ srcSorted, const int* __restrict__ deg,
    const int* __restrict__ rowBeg, const unsigned short* __restrict__ z2l,
    const float* __restrict__ z2r, const float* __restrict__ b2,
    __half* __restrict__ h2) {
  int tid = blockIdx.x * 256 + threadIdx.x;
  int n = tid >> 2;
  int q = tid & 3;
  if (n >= N_NODES) return;
  int beg = rowBeg[n];
  int dg = deg[n];
  int end = beg + dg;
  int acc0 = 0, acc1 = 0, acc2 = 0, acc3 = 0;
  int i = beg;
  for (; i + 8 <= end; i += 8) {
    int sqa = srcSorted[i + q];
    int sqb = srcSorted[i + 4 + q];
#pragma unroll
    for (int j = 0; j < 4; ++j) {
      int sa = __shfl(sqa, j, 4);
      int sb = __shfl(sqb, j, 4);
      uint2 va = *(const uint2*)(z2l + (size_t)sa * H + q * 4);
      uint2 vb = *(const uint2*)(z2l + (size_t)sb * H + q * 4);
      acc0 += (((int)(va.x << 16)) >> 16) + (((int)(vb.x << 16)) >> 16);
      acc1 += (((int)va.x) >> 16) + (((int)vb.x) >> 16);
      acc2 += (((int)(va.y << 16)) >> 16) + (((int)(vb.y << 16)) >> 16);
      acc3 += (((int)va.y) >> 16) + (((int)vb.y) >> 16);
    }
  }
  for (; i + 4 <= end; i += 4) {
    int sq = srcSorted[i + q];
#pragma unroll
    for (int j = 0; j < 4; ++j) {
      int sj = __shfl(sq, j, 4);
      uint2 v = *(const uint2*)(z2l + (size_t)sj * H + q * 4);
      acc0 += ((int)(v.x << 16)) >> 16;
      acc1 += ((int)v.x) >> 16;
      acc2 += ((int)(v.y << 16)) >> 16;
      acc3 += ((int)v.y) >> 16;
    }
  }
  for (; i < end; ++i) {
    int sj = srcSorted[i];
    uint2 v = *(const uint2*)(z2l + (size_t)sj * H + q * 4);
    acc0 += ((int)(v.x << 16)) >> 16;
    acc1 += ((int)v.x) >> 16;
    acc2 += ((int)(v.y << 16)) >> 16;
    acc3 += ((int)v.y) >> 16;
  }
  float s = (1.f / fmaxf((float)dg, 1.f)) * QINV;
  float4 zr = *(const float4*)(z2r + (size_t)n * H + q * 4);
  float4 bb = *(const float4*)(b2 + q * 4);
  float v0 = fmaf((float)acc0, s, bb.x + zr.x);
  float v1 = fmaf((float)acc1, s, bb.y + zr.y);
  float v2 = fmaf((float)acc2, s, bb.z + zr.z);
  float v3 = fmaf((float)acc3, s, bb.w + zr.w);
  __half2 h0 = __floats2half2_rn(v0, v1);
  __half2 h1 = __floats2half2_rn(v2, v3);
  uint2 pk;
  pk.x = *(unsigned int*)&h0;
  pk.y = *(unsigned int*)&h1;
  *(uint2*)(h2 + (size_t)n * H + q * 4) = pk;
}

// ---------------------------------------------------------------------------
// decode (2 pairs/thread): out[p] = sigmoid(dot(h2[s], h2[d]))
// int2 index loads + float2 store halve the non-row mem-inst count.
// ---------------------------------------------------------------------------
__device__ inline float dot8h(uint4 u, uint4 v) {
  float acc = 0.f;
  const unsigned int* uw = (const unsigned int*)&u;
  const unsigned int* vw = (const unsigned int*)&v;
#pragma unroll
  for (int j = 0; j < 4; ++j) {
    float2 a = __half22float2(*(const __half2*)&uw[j]);
    float2 b = __half22float2(*(const __half2*)&vw[j]);
    acc = fmaf(a.x, b.x, acc);
    acc = fmaf(a.y, b.y, acc);
  }
  return acc;
}

__global__ void __launch_bounds__(256) k_decode(
    const int* __restrict__ ps, const int* __restrict__ pd,
    const __half* __restrict__ h2, float* __restrict__ out, int P) {
  int t = blockIdx.x * 256 + threadIdx.x;
  int p = t * 2;
  if (p >= P) return;
  int2 av = *(const int2*)(ps + p);
  int2 bv = *(const int2*)(pd + p);
  const uint4* ha0 = (const uint4*)(h2 + (size_t)av.x * H);
  const uint4* hb0 = (const uint4*)(h2 + (size_t)bv.x * H);
  const uint4* ha1 = (const uint4*)(h2 + (size_t)av.y * H);
  const uint4* hb1 = (const uint4*)(h2 + (size_t)bv.y * H);
  uint4 u00 = ha0[0], u01 = ha0[1];
  uint4 v00 = hb0[0], v01 = hb0[1];
  uint4 u10 = ha1[0], u11 = ha1[1];
  uint4 v10 = hb1[0], v11 = hb1[1];
  float d0 = dot8h(u00, v00) + dot8h(u01, v01);
  float d1 = dot8h(u10, v10) + dot8h(u11, v11);
  float o0 = 1.f / (1.f + __expf(-d0));
  float o1 = 1.f / (1.f + __expf(-d1));
  if (p + 1 < P) {
    *(float2*)(out + p) = make_float2(o0, o1);
  } else {
    out[p] = o0;
  }
}

// ---------------------------------------------------------------------------
extern "C" void kernel_launch(void* const* d_in, const int* in_sizes, int n_in,
                              void* d_out, int out_size, void* d_ws, size_t ws_size,
                              hipStream_t stream) {
  const float* x   = (const float*)d_in[0];
  const float* W1l = (const float*)d_in[1];
  const float* b1  = (const float*)d_in[2];
  const float* W1r = (const float*)d_in[3];
  const float* W2l = (const float*)d_in[4];
  const float* b2  = (const float*)d_in[5];
  const float* W2r = (const float*)d_in[6];
  const int* ei = (const int*)d_in[7];  // [2, E] int32
  const int* di = (const int*)d_in[8];  // [2, P] int32
  const int E = in_sizes[7] / 2;
  const int P = in_sizes[8] / 2;

  const size_t NF = (size_t)N_NODES * H;
  // Gathered tables (3.2 MB each, L2-resident): y1l/z2l int16 fixed-point,
  // h2 fp16. h2 aliases y1l (dead after gather1). y1r fp32 aliases z2r
  // (same thread+element).
  unsigned short* y1l = (unsigned short*)d_ws;   // NF
  __half*         h2  = (__half*)y1l;            // alias
  unsigned short* z2l = y1l + NF;                // NF
  float*  y1r = (float*)(z2l + NF);              // NF floats
  float*  z2r = y1r;                             // alias
  int* recs   = (int*)(y1r + NF);                // NBIN * BINCAP
  int* binCur = recs + (size_t)NBIN * BINCAP;    // NBIN (padded to 512)
  int* deg    = binCur + 512;                    // N
  int* rowBeg = deg + N_NODES;                   // N

  const int fillBlocks = (E + ECHUNK - 1) / ECHUNK;
  const int frontBlocks = LIN1B + fillBlocks;
  const int gatherBlocks = ((N_NODES * 4) + 255) / 256;   // 4 lanes/node
  const int decodeBlocks = ((P + 1) / 2 + 255) / 256;     // 2 pairs/thread

  k_init<<<1, 512, 0, stream>>>(binCur);
  k_front<<<frontBlocks, 256, 0, stream>>>(x, W1l, W1r, y1l, y1r,
                                           ei, ei + E, binCur, recs, E);
  k_group<<<NBIN, 512, 0, stream>>>(recs, binCur, deg, rowBeg);
  k_gather1<<<gatherBlocks, 256, 0, stream>>>(recs, deg, rowBeg, y1l, y1r,
                                              b1, W2l, W2r, z2l, z2r);
  k_gather2<<<gatherBlocks, 256, 0, stream>>>(recs, deg, rowBeg, z2l, z2r,
                                              b2, h2);
  k_decode<<<decodeBlocks, 256, 0, stream>>>(di, di + P, h2, (float*)d_out, P);
}

// Round 12
// 213.554 us; speedup vs baseline: 1.0560x; 1.0560x over previous
//
#include <hip/hip_runtime.h>
#include <hip/hip_fp16.h>

#define N_NODES 100000
#define F_IN 128
#define H 16
#define NBIN 391           // ceil(N_NODES/256); bin b owns nodes [b*256, b*256+256)
#define BINCAP 4608        // per-bin record capacity (mean 4096, +8 sigma)
#define ECHUNK 8192        // edges per binfill block (512 thr x 16)
#define QSCALE 4096.0f     // int16 fixed-point scale (range ±8, err 1.2e-4)
#define QINV (1.0f / 4096.0f)

// Pack two floats to int16 fixed-point (round-nearest, clamped)
__device__ inline unsigned int packi16(float a, float b) {
  int ia = __float2int_rn(fminf(fmaxf(a * QSCALE, -32767.f), 32767.f));
  int ib = __float2int_rn(fminf(fmaxf(b * QSCALE, -32767.f), 32767.f));
  return (unsigned int)((ia & 0xffff) | (ib << 16));
}

// ---------------------------------------------------------------------------
// k_init: binCur[b] = b * BINCAP  (record-region cursors)
// ---------------------------------------------------------------------------
__global__ void __launch_bounds__(512) k_init(int* __restrict__ binCur) {
  int t = threadIdx.x;
  if (t < NBIN) binCur[t] = t * BINCAP;
}

// ---------------------------------------------------------------------------
// k_lin1 (v4, split-K=4): y1l = i16fx(x @ W1l), y1r = x @ W1r (fp32).
// 256 thr = 4 waves x 64 nodes; wave w handles K-quarter w (wave-uniform ->
// W scalar-loaded, only 4 KB W per wave -> K$-resident -> FMA-bound, fixing
// v3's SMEM-streaming stall at 2048 W values/wave). x read exactly once
// (8 up-front float4/thread for MLP). Waves 1-3 write partials to LDS
// [ch][node] (conflict-free); wave 0 reduces in FIXED source order
// ((p0+p1)+p2)+p3 -> bitwise deterministic.
// ---------------------------------------------------------------------------
__global__ void __launch_bounds__(256) k_lin1(
    const float* __restrict__ x, const float* __restrict__ W1l,
    const float* __restrict__ W1r, unsigned short* __restrict__ y1l,
    float* __restrict__ y1r) {
  __shared__ float red[3 * 32 * 64];   // 24 KB: [part-1][ch 0..31][node 0..63]
  int t = threadIdx.x;
  int part = __builtin_amdgcn_readfirstlane(t >> 6);   // wave index 0..3
  int ln = t & 63;
  int n = blockIdx.x * 64 + ln;
  int nc = (n < N_NODES) ? n : (N_NODES - 1);          // clamp; stores guarded
  const float4* xr = (const float4*)(x + (size_t)nc * F_IN + part * (F_IN / 4));
  float4 xv[8];
#pragma unroll
  for (int j = 0; j < 8; ++j) xv[j] = xr[j];
  const float* Wl = W1l + part * (F_IN / 4) * H;       // SGPR base, 2 KB
  const float* Wr = W1r + part * (F_IN / 4) * H;       // SGPR base, 2 KB
  float al[H], ar[H];
#pragma unroll
  for (int c = 0; c < H; ++c) { al[c] = 0.f; ar[c] = 0.f; }
#pragma unroll
  for (int j = 0; j < 8; ++j) {
    float xs[4] = {xv[j].x, xv[j].y, xv[j].z, xv[j].w};
#pragma unroll
    for (int jj = 0; jj < 4; ++jj) {
      int k = j * 4 + jj;
#pragma unroll
      for (int c = 0; c < H; ++c) {
        al[c] = fmaf(xs[jj], Wl[k * H + c], al[c]);
        ar[c] = fmaf(xs[jj], Wr[k * H + c], ar[c]);
      }
    }
  }
  if (part != 0) {
    int base = (part - 1) * 2048;
#pragma unroll
    for (int c = 0; c < H; ++c) {
      red[base + c * 64 + ln] = al[c];
      red[base + (H + c) * 64 + ln] = ar[c];
    }
  }
  __syncthreads();
  if (part == 0 && n < N_NODES) {
#pragma unroll
    for (int c = 0; c < H; ++c) {
      al[c] = ((al[c] + red[c * 64 + ln]) + red[2048 + c * 64 + ln])
              + red[4096 + c * 64 + ln];
      ar[c] = ((ar[c] + red[(H + c) * 64 + ln]) + red[2048 + (H + c) * 64 + ln])
              + red[4096 + (H + c) * 64 + ln];
    }
    uint4 w0, w1;
    w0.x = packi16(al[0], al[1]);  w0.y = packi16(al[2], al[3]);
    w0.z = packi16(al[4], al[5]);  w0.w = packi16(al[6], al[7]);
    w1.x = packi16(al[8], al[9]);  w1.y = packi16(al[10], al[11]);
    w1.z = packi16(al[12], al[13]); w1.w = packi16(al[14], al[15]);
    uint4* ol = (uint4*)(y1l + (size_t)n * H);   // 32 B row
    ol[0] = w0;
    ol[1] = w1;
    float4* orr = (float4*)(y1r + (size_t)n * H);
#pragma unroll
    for (int q = 0; q < 4; ++q)
      orr[q] = make_float4(ar[4 * q], ar[4 * q + 1], ar[4 * q + 2], ar[4 * q + 3]);
  }
}

// ---------------------------------------------------------------------------
// k_binfill: radix pass 1 — bin records (src<<8 | dstLow) by dst>>8.
// 512 thr x 16 edges -> 196 blocks -> 77k per-(block,bin) reservation
// atomics (4x fewer than R11's 306k same-address L2 atomics).
// Record ORDER is nondeterministic; record SET is deterministic — fine,
// downstream accumulation is integer (order-invariant).
// ---------------------------------------------------------------------------
__global__ void __launch_bounds__(512) k_binfill(
    const int* __restrict__ src, const int* __restrict__ dst,
    int* __restrict__ binCur, int* __restrict__ recs, int E) {
  __shared__ int hist[512];
  __shared__ int gbase[512];
  __shared__ int cnt2[512];
  int t = threadIdx.x;
  hist[t] = 0;
  cnt2[t] = 0;
  __syncthreads();
  int base = blockIdx.x * ECHUNK;
  int rec[16], bin[16];
#pragma unroll
  for (int j = 0; j < 16; ++j) {
    int e = base + j * 512 + t;
    if (e < E) {
      int s = src[e];
      int d = dst[e];
      rec[j] = (s << 8) | (d & 255);
      bin[j] = d >> 8;
      atomicAdd(&hist[bin[j]], 1);
    } else {
      bin[j] = -1;
    }
  }
  __syncthreads();
  if (t < NBIN) {
    int c = hist[t];
    gbase[t] = (c > 0) ? atomicAdd(&binCur[t], c) : 0;
  }
  __syncthreads();
#pragma unroll
  for (int j = 0; j < 16; ++j) {
    if (bin[j] >= 0) {
      int loc = atomicAdd(&cnt2[bin[j]], 1);
      int slot = gbase[bin[j]] + loc;
      if (slot < (bin[j] + 1) * BINCAP)  // safety clamp (never expected)
        recs[slot] = rec[j];
    }
  }
}

// ---------------------------------------------------------------------------
// k_group: one block per bin. Load records to LDS, histogram dstLow,
// scan -> deg/rowBeg, scatter src ids directly to final global CSR slots.
// Row-internal order nondeterministic — fine (integer accumulation).
// ---------------------------------------------------------------------------
__global__ void __launch_bounds__(512) k_group(
    int* __restrict__ recs, const int* __restrict__ binCur,
    int* __restrict__ deg, int* __restrict__ rowBeg) {
  __shared__ int lrec[BINCAP];
  __shared__ int hist[256];
  __shared__ int off[256];       // inclusive scan; (off - hist) = exclusive
  __shared__ int cur[256];
  int t = threadIdx.x;
  int b = blockIdx.x;
  int rbase = b * BINCAP;
  int R = binCur[b] - rbase;
  if (R > BINCAP) R = BINCAP;
  if (t < 256) hist[t] = 0;
  __syncthreads();
#pragma unroll
  for (int j = 0; j < 9; ++j) {
    int idx = j * 512 + t;
    if (idx < R) {
      int r = recs[rbase + idx];
      lrec[idx] = r;
      atomicAdd(&hist[r & 255], 1);
    }
  }
  __syncthreads();
  if (t < 256) off[t] = hist[t];
  __syncthreads();
  for (int o = 1; o < 256; o <<= 1) {
    int u = 0;
    if (t < 256 && t >= o) u = off[t - o];
    __syncthreads();
    if (t < 256) off[t] += u;
    __syncthreads();
  }
  if (t < 256) {
    int ex = off[t] - hist[t];
    cur[t] = ex;
    int n = (b << 8) + t;
    if (n < N_NODES) {
      deg[n] = hist[t];
      rowBeg[n] = rbase + ex;
    }
  }
  __syncthreads();
#pragma unroll
  for (int j = 0; j < 9; ++j) {
    int idx = j * 512 + t;
    if (idx < R) {
      int r = lrec[idx];
      int slot = atomicAdd(&cur[r & 255], 1);
      recs[rbase + slot] = r >> 8;   // direct final write (L2-local region)
    }
  }
}

// ---------------------------------------------------------------------------
// gather1 (4 lanes/node): lane q owns channels 4q..4q+3. Per neighbor one
// uint2 (4 int16) load; int32 accumulation (exact, order-invariant).
// 8-deep neighbor unroll. Epilogue: h1 = relu(mean + b1 + y1r); W2 matvec
// via width-4 shuffle transpose; z2l = i16fx, z2r = fp32.
// ---------------------------------------------------------------------------
__global__ void __launch_bounds__(256) k_gather1(
    const int* __restrict__ srcSorted, const int* __restrict__ deg,
    const int* __restrict__ rowBeg, const unsigned short* __restrict__ y1l,
    const float* __restrict__ y1r, const float* __restrict__ b1,
    const float* __restrict__ W2l, const float* __restrict__ W2r,
    unsigned short* __restrict__ z2l, float* __restrict__ z2r) {
  int tid = blockIdx.x * 256 + threadIdx.x;
  int n = tid >> 2;
  int q = tid & 3;
  if (n >= N_NODES) return;
  int beg = rowBeg[n];
  int dg = deg[n];
  int end = beg + dg;
  int acc0 = 0, acc1 = 0, acc2 = 0, acc3 = 0;
  int i = beg;
  for (; i + 8 <= end; i += 8) {
    int sqa = srcSorted[i + q];
    int sqb = srcSorted[i + 4 + q];
#pragma unroll
    for (int j = 0; j < 4; ++j) {
      int sa = __shfl(sqa, j, 4);
      int sb = __shfl(sqb, j, 4);
      uint2 va = *(const uint2*)(y1l + (size_t)sa * H + q * 4);
      uint2 vb = *(const uint2*)(y1l + (size_t)sb * H + q * 4);
      acc0 += (((int)(va.x << 16)) >> 16) + (((int)(vb.x << 16)) >> 16);
      acc1 += (((int)va.x) >> 16) + (((int)vb.x) >> 16);
      acc2 += (((int)(va.y << 16)) >> 16) + (((int)(vb.y << 16)) >> 16);
      acc3 += (((int)va.y) >> 16) + (((int)vb.y) >> 16);
    }
  }
  for (; i + 4 <= end; i += 4) {
    int sq = srcSorted[i + q];
#pragma unroll
    for (int j = 0; j < 4; ++j) {
      int sj = __shfl(sq, j, 4);
      uint2 v = *(const uint2*)(y1l + (size_t)sj * H + q * 4);
      acc0 += ((int)(v.x << 16)) >> 16;
      acc1 += ((int)v.x) >> 16;
      acc2 += ((int)(v.y << 16)) >> 16;
      acc3 += ((int)v.y) >> 16;
    }
  }
  for (; i < end; ++i) {
    int sj = srcSorted[i];
    uint2 v = *(const uint2*)(y1l + (size_t)sj * H + q * 4);
    acc0 += ((int)(v.x << 16)) >> 16;
    acc1 += ((int)v.x) >> 16;
    acc2 += ((int)(v.y << 16)) >> 16;
    acc3 += ((int)v.y) >> 16;
  }
  float s = (1.f / fmaxf((float)dg, 1.f)) * QINV;
  float4 yr = *(const float4*)(y1r + (size_t)n * H + q * 4);
  float4 bb = *(const float4*)(b1 + q * 4);
  float h1x = fmaxf(fmaf((float)acc0, s, bb.x + yr.x), 0.f);
  float h1y = fmaxf(fmaf((float)acc1, s, bb.y + yr.y), 0.f);
  float h1z = fmaxf(fmaf((float)acc2, s, bb.z + yr.z), 0.f);
  float h1w = fmaxf(fmaf((float)acc3, s, bb.w + yr.w), 0.f);
  float zl0 = 0.f, zl1 = 0.f, zl2 = 0.f, zl3 = 0.f;
  float zr0 = 0.f, zr1 = 0.f, zr2 = 0.f, zr3 = 0.f;
#pragma unroll
  for (int sl = 0; sl < 4; ++sl) {
    float hx = __shfl(h1x, sl, 4);
    float hy = __shfl(h1y, sl, 4);
    float hz = __shfl(h1z, sl, 4);
    float hw = __shfl(h1w, sl, 4);
    float hk4[4] = {hx, hy, hz, hw};
#pragma unroll
    for (int j = 0; j < 4; ++j) {
      int k = sl * 4 + j;               // h1 channel index
      float4 wl = *(const float4*)(W2l + k * H + q * 4);
      float4 wr = *(const float4*)(W2r + k * H + q * 4);
      float hk = hk4[j];
      zl0 = fmaf(hk, wl.x, zl0); zl1 = fmaf(hk, wl.y, zl1);
      zl2 = fmaf(hk, wl.z, zl2); zl3 = fmaf(hk, wl.w, zl3);
      zr0 = fmaf(hk, wr.x, zr0); zr1 = fmaf(hk, wr.y, zr1);
      zr2 = fmaf(hk, wr.z, zr2); zr3 = fmaf(hk, wr.w, zr3);
    }
  }
  uint2 pk;
  pk.x = packi16(zl0, zl1);
  pk.y = packi16(zl2, zl3);
  *(uint2*)(z2l + (size_t)n * H + q * 4) = pk;
  *(float4*)(z2r + (size_t)n * H + q * 4) = make_float4(zr0, zr1, zr2, zr3);
}

// ---------------------------------------------------------------------------
// gather2 (4 lanes/node): h2 = fp16(mean(z2l_nbrs) + b2 + z2r)
// ---------------------------------------------------------------------------
__global__ void __launch_bounds__(256) k_gather2(
    const int* __restrict__ srcSorted, const int* __restrict__ deg,
    const int* __restrict__ rowBeg, const unsigned short* __restrict__ z2l,
    const float* __restrict__ z2r, const float* __restrict__ b2,
    __half* __restrict__ h2) {
  int tid = blockIdx.x * 256 + threadIdx.x;
  int n = tid >> 2;
  int q = tid & 3;
  if (n >= N_NODES) return;
  int beg = rowBeg[n];
  int dg = deg[n];
  int end = beg + dg;
  int acc0 = 0, acc1 = 0, acc2 = 0, acc3 = 0;
  int i = beg;
  for (; i + 8 <= end; i += 8) {
    int sqa = srcSorted[i + q];
    int sqb = srcSorted[i + 4 + q];
#pragma unroll
    for (int j = 0; j < 4; ++j) {
      int sa = __shfl(sqa, j, 4);
      int sb = __shfl(sqb, j, 4);
      uint2 va = *(const uint2*)(z2l + (size_t)sa * H + q * 4);
      uint2 vb = *(const uint2*)(z2l + (size_t)sb * H + q * 4);
      acc0 += (((int)(va.x << 16)) >> 16) + (((int)(vb.x << 16)) >> 16);
      acc1 += (((int)va.x) >> 16) + (((int)vb.x) >> 16);
      acc2 += (((int)(va.y << 16)) >> 16) + (((int)(vb.y << 16)) >> 16);
      acc3 += (((int)va.y) >> 16) + (((int)vb.y) >> 16);
    }
  }
  for (; i + 4 <= end; i += 4) {
    int sq = srcSorted[i + q];
#pragma unroll
    for (int j = 0; j < 4; ++j) {
      int sj = __shfl(sq, j, 4);
      uint2 v = *(const uint2*)(z2l + (size_t)sj * H + q * 4);
      acc0 += ((int)(v.x << 16)) >> 16;
      acc1 += ((int)v.x) >> 16;
      acc2 += ((int)(v.y << 16)) >> 16;
      acc3 += ((int)v.y) >> 16;
    }
  }
  for (; i < end; ++i) {
    int sj = srcSorted[i];
    uint2 v = *(const uint2*)(z2l + (size_t)sj * H + q * 4);
    acc0 += ((int)(v.x << 16)) >> 16;
    acc1 += ((int)v.x) >> 16;
    acc2 += ((int)(v.y << 16)) >> 16;
    acc3 += ((int)v.y) >> 16;
  }
  float s = (1.f / fmaxf((float)dg, 1.f)) * QINV;
  float4 zr = *(const float4*)(z2r + (size_t)n * H + q * 4);
  float4 bb = *(const float4*)(b2 + q * 4);
  float v0 = fmaf((float)acc0, s, bb.x + zr.x);
  float v1 = fmaf((float)acc1, s, bb.y + zr.y);
  float v2 = fmaf((float)acc2, s, bb.z + zr.z);
  float v3 = fmaf((float)acc3, s, bb.w + zr.w);
  __half2 h0 = __floats2half2_rn(v0, v1);
  __half2 h1 = __floats2half2_rn(v2, v3);
  uint2 pk;
  pk.x = *(unsigned int*)&h0;
  pk.y = *(unsigned int*)&h1;
  *(uint2*)(h2 + (size_t)n * H + q * 4) = pk;
}

// ---------------------------------------------------------------------------
// decode (2 pairs/thread): out[p] = sigmoid(dot(h2[s], h2[d]))
// ---------------------------------------------------------------------------
__device__ inline float dot8h(uint4 u, uint4 v) {
  float acc = 0.f;
  const unsigned int* uw = (const unsigned int*)&u;
  const unsigned int* vw = (const unsigned int*)&v;
#pragma unroll
  for (int j = 0; j < 4; ++j) {
    float2 a = __half22float2(*(const __half2*)&uw[j]);
    float2 b = __half22float2(*(const __half2*)&vw[j]);
    acc = fmaf(a.x, b.x, acc);
    acc = fmaf(a.y, b.y, acc);
  }
  return acc;
}

__global__ void __launch_bounds__(256) k_decode(
    const int* __restrict__ ps, const int* __restrict__ pd,
    const __half* __restrict__ h2, float* __restrict__ out, int P) {
  int t = blockIdx.x * 256 + threadIdx.x;
  int p = t * 2;
  if (p >= P) return;
  int2 av = *(const int2*)(ps + p);
  int2 bv = *(const int2*)(pd + p);
  const uint4* ha0 = (const uint4*)(h2 + (size_t)av.x * H);
  const uint4* hb0 = (const uint4*)(h2 + (size_t)bv.x * H);
  const uint4* ha1 = (const uint4*)(h2 + (size_t)av.y * H);
  const uint4* hb1 = (const uint4*)(h2 + (size_t)bv.y * H);
  uint4 u00 = ha0[0], u01 = ha0[1];
  uint4 v00 = hb0[0], v01 = hb0[1];
  uint4 u10 = ha1[0], u11 = ha1[1];
  uint4 v10 = hb1[0], v11 = hb1[1];
  float d0 = dot8h(u00, v00) + dot8h(u01, v01);
  float d1 = dot8h(u10, v10) + dot8h(u11, v11);
  float o0 = 1.f / (1.f + __expf(-d0));
  float o1 = 1.f / (1.f + __expf(-d1));
  if (p + 1 < P) {
    *(float2*)(out + p) = make_float2(o0, o1);
  } else {
    out[p] = o0;
  }
}

// ---------------------------------------------------------------------------
extern "C" void kernel_launch(void* const* d_in, const int* in_sizes, int n_in,
                              void* d_out, int out_size, void* d_ws, size_t ws_size,
                              hipStream_t stream) {
  const float* x   = (const float*)d_in[0];
  const float* W1l = (const float*)d_in[1];
  const float* b1  = (const float*)d_in[2];
  const float* W1r = (const float*)d_in[3];
  const float* W2l = (const float*)d_in[4];
  const float* b2  = (const float*)d_in[5];
  const float* W2r = (const float*)d_in[6];
  const int* ei = (const int*)d_in[7];  // [2, E] int32
  const int* di = (const int*)d_in[8];  // [2, P] int32
  const int E = in_sizes[7] / 2;
  const int P = in_sizes[8] / 2;

  const size_t NF = (size_t)N_NODES * H;
  // Gathered tables (3.2 MB each, L2-resident): y1l/z2l int16 fixed-point,
  // h2 fp16. h2 aliases y1l (dead after gather1). y1r fp32 aliases z2r
  // (same thread+element).
  unsigned short* y1l = (unsigned short*)d_ws;   // NF
  __half*         h2  = (__half*)y1l;            // alias
  unsigned short* z2l = y1l + NF;                // NF
  float*  y1r = (float*)(z2l + NF);              // NF floats
  float*  z2r = y1r;                             // alias
  int* recs   = (int*)(y1r + NF);                // NBIN * BINCAP
  int* binCur = recs + (size_t)NBIN * BINCAP;    // NBIN (padded to 512)
  int* deg    = binCur + 512;                    // N
  int* rowBeg = deg + N_NODES;                   // N

  const int lin1Blocks = (N_NODES + 63) / 64;    // 64 nodes per 256-thr block
  const int fillBlocks = (E + ECHUNK - 1) / ECHUNK;
  const int gatherBlocks = ((N_NODES * 4) + 255) / 256;   // 4 lanes/node
  const int decodeBlocks = ((P + 1) / 2 + 255) / 256;     // 2 pairs/thread

  k_init<<<1, 512, 0, stream>>>(binCur);
  k_lin1<<<lin1Blocks, 256, 0, stream>>>(x, W1l, W1r, y1l, y1r);
  k_binfill<<<fillBlocks, 512, 0, stream>>>(ei, ei + E, binCur, recs, E);
  k_group<<<NBIN, 512, 0, stream>>>(recs, binCur, deg, rowBeg);
  k_gather1<<<gatherBlocks, 256, 0, stream>>>(recs, deg, rowBeg, y1l, y1r,
                                              b1, W2l, W2r, z2l, z2r);
  k_gather2<<<gatherBlocks, 256, 0, stream>>>(recs, deg, rowBeg, z2l, z2r,
                                              b2, h2);
  k_decode<<<decodeBlocks, 256, 0, stream>>>(di, di + P, h2, (float*)d_out, P);
}